// Round 8
// baseline (135.610 us; speedup 1.0000x reference)
//
#include <hip/hip_runtime.h>
#include <math.h>

#define DD 4096
#define EE 64
#define BK 64
#define TAU 1e-4f
#define NEG_SENTINEL -1.0e30f
#define MAXFIX 16000

typedef __attribute__((ext_vector_type(8))) short short8v;
typedef __attribute__((ext_vector_type(4))) float f32x4;

union BF8 {
  uint4 u;
  short8v s;
};

__device__ __forceinline__ unsigned asu(float f) {
  union { float f; unsigned u; } v; v.f = f; return v.u;
}
__device__ __forceinline__ float asf(unsigned u) {
  union { unsigned u; float f; } v; v.u = u; return v.f;
}

// Split 8 f32 into hi/lo bf16 (RNE both): x = hi + lo + O(2^-17 |x|).
__device__ __forceinline__ void split8(const float x[8], uint4& hi, uint4& lo) {
  unsigned h[8], l[8];
#pragma unroll
  for (int j = 0; j < 8; j++) {
    unsigned u = asu(x[j]);
    unsigned r = (u + 0x7fffu + ((u >> 16) & 1u)) & 0xffff0000u;
    h[j] = r;
    unsigned v = asu(x[j] - asf(r));
    l[j] = (v + 0x7fffu + ((v >> 16) & 1u)) & 0xffff0000u;
  }
  hi = make_uint4((h[0] >> 16) | h[1], (h[2] >> 16) | h[3],
                  (h[4] >> 16) | h[5], (h[6] >> 16) | h[7]);
  lo = make_uint4((l[0] >> 16) | l[1], (l[2] >> 16) | l[3],
                  (l[4] >> 16) | l[5], (l[6] >> 16) | l[7]);
}

// global -> LDS direct copy, 16B/lane; LDS dest wave-uniform (HW adds l*16).
__device__ __forceinline__ void gload16(const void* g, void* l) {
  __builtin_amdgcn_global_load_lds(
      (const __attribute__((address_space(1))) uint32_t*)(uintptr_t)g,
      (__attribute__((address_space(3))) uint32_t*)(uint32_t)(uintptr_t)l, 16,
      0, 0);
}

// ---------------------------------------------------------------------------
// Kernel 1 (R8): bf16-split MFMA partial GEMM, m97-style A staging.
// Tile: BM=64 rows x 64 experts x BK=64. 4 waves; wave = 16 rows (mt=1,nt=4).
// A: f32 in LDS via global_load_lds, [64 rows][256B], 16B-slot swizzle
//    phys = slot ^ (row&15) realized by pre-swizzled per-lane SOURCE
//    (linear dest; each instr = 4 complete rows x 256B windows -> DRAM sees
//    contiguous 256B chunks). Frags read f32 + split to bf16 in-register.
// B: reg-staged (R7 path), split once, hi/lo bf16 LDS planes [64e][128B],
//    slot swizzle phys = slot ^ (e&7). Double-buffered both: LDS = 64 KB.
// One __syncthreads per step; A-loads in flight across full compute phase.
// ---------------------------------------------------------------------------
template <int KSPLIT>
__global__ __launch_bounds__(256, 2) void gemm_mfma(
    const float* __restrict__ hidden, const float* __restrict__ gate_w,
    float* __restrict__ part, int nrows) {
  __shared__ __align__(16) char smem[65536];  // A: 2x16K @0, B: 2x16K @32768

  const int tid = threadIdx.x;
  const int lane = tid & 63;
  const int wv = tid >> 6;
  const int fr = lane & 15;
  const int fg = (lane >> 4) & 3;
  const int m0 = blockIdx.x * 64;
  const int kslice = DD / KSPLIT;
  const int nsteps = kslice / BK;
  const int k0 = blockIdx.y * kslice;

  // A staging sources: wave wv stages rows 16wv..16wv+15, instr i = rows
  // 16wv+4i..+3. Lane l -> row 16wv+4i+(l>>4), source slot (l&15)^(rsw),
  // rsw = (4i+(l>>4))&15  (the 16wv part drops out of row&15).
  const float* srcA[4];
#pragma unroll
  for (int i = 0; i < 4; i++) {
    const int rloc = 4 * i + (lane >> 4);           // 0..15 within wave
    const int r = 16 * wv + rloc;                   // block-local row
    const int s = (lane & 15) ^ (rloc & 15);        // source 16B slot
    srcA[i] = hidden + (size_t)(m0 + r) * DD + k0 + s * 4;
  }
  auto stageA = [&](int bsel, int t) {
    char* dst = smem + bsel * 16384 + wv * 4096;
#pragma unroll
    for (int i = 0; i < 4; i++) gload16(srcA[i] + t * BK, dst + i * 1024);
  };

  // B staging: thread owns (expert e, k-quarter q: 16 floats at k=q*16).
  const int be = tid & 63;
  const int bq = tid >> 6;
  const float* pB = gate_w + (size_t)be * DD + k0 + bq * 16;
  const int bw0 = be * 128 + (((2 * bq + 0) ^ (be & 7)) << 4);
  const int bw1 = be * 128 + (((2 * bq + 1) ^ (be & 7)) << 4);

  float4 bn[4];
  auto loadB = [&](int t) {
#pragma unroll
    for (int i = 0; i < 4; i++) bn[i] = *(const float4*)(pB + t * BK + 4 * i);
  };
  auto stageB = [&](int bsel) {  // writes B(t) currently held in bn
    char* Bb = smem + 32768 + bsel * 16384;
    float x0[8] = {bn[0].x, bn[0].y, bn[0].z, bn[0].w,
                   bn[1].x, bn[1].y, bn[1].z, bn[1].w};
    float x1[8] = {bn[2].x, bn[2].y, bn[2].z, bn[2].w,
                   bn[3].x, bn[3].y, bn[3].z, bn[3].w};
    uint4 h0, l0, h1, l1;
    split8(x0, h0, l0);
    split8(x1, h1, l1);
    *(uint4*)(Bb + bw0) = h0;
    *(uint4*)(Bb + bw1) = h1;
    *(uint4*)(Bb + 8192 + bw0) = l0;
    *(uint4*)(Bb + 8192 + bw1) = l1;
  };

  // ---- prologue ----
  loadB(0);
  stageA(0, 0);
  stageB(0);
  loadB(1);
  __syncthreads();

  f32x4 zero4 = {0.f, 0.f, 0.f, 0.f};
  f32x4 acc[4];
#pragma unroll
  for (int nt = 0; nt < 4; nt++) acc[nt] = zero4;

  const int arow = (16 * wv + fr) * 256;

  int buf = 0;
  for (int t = 0; t < nsteps; t++) {
    if (t + 1 < nsteps) {
      stageB(buf ^ 1);       // ds_write B(t+1) from bn
      stageA(buf ^ 1, t + 1);  // async A(t+1)
    }
    if (t + 2 < nsteps) loadB(t + 2);

    const char* Ab = smem + buf * 16384;
    const char* Bb = smem + 32768 + buf * 16384;
#pragma unroll
    for (int c = 0; c < 2; c++) {
      // A frag: 8 consecutive k-floats via two swizzled b128 reads
      float4 a0 = *(const float4*)(Ab + arow + (((c * 8 + fg * 2 + 0) ^ fr) << 4));
      float4 a1 = *(const float4*)(Ab + arow + (((c * 8 + fg * 2 + 1) ^ fr) << 4));
      float xa[8] = {a0.x, a0.y, a0.z, a0.w, a1.x, a1.y, a1.z, a1.w};
      BF8 ah, al;
      split8(xa, ah.u, al.u);
      BF8 bh[4], bl[4];
#pragma unroll
      for (int nt = 0; nt < 4; nt++) {
        const int boff = (nt * 16 + fr) * 128 + (((c * 4 + fg) ^ (fr & 7)) << 4);
        bh[nt].u = *(const uint4*)(Bb + boff);
        bl[nt].u = *(const uint4*)(Bb + 8192 + boff);
      }
#pragma unroll
      for (int nt = 0; nt < 4; nt++)
        acc[nt] = __builtin_amdgcn_mfma_f32_16x16x32_bf16(ah.s, bh[nt].s,
                                                          acc[nt], 0, 0, 0);
#pragma unroll
      for (int nt = 0; nt < 4; nt++)
        acc[nt] = __builtin_amdgcn_mfma_f32_16x16x32_bf16(ah.s, bl[nt].s,
                                                          acc[nt], 0, 0, 0);
#pragma unroll
      for (int nt = 0; nt < 4; nt++)
        acc[nt] = __builtin_amdgcn_mfma_f32_16x16x32_bf16(al.s, bh[nt].s,
                                                          acc[nt], 0, 0, 0);
    }
    __syncthreads();
    buf ^= 1;
  }

  // partial logits: part[ks][row][e]; C/D: row=(l>>4)*4+j, col=l&15
  float* dst = part + (size_t)blockIdx.y * nrows * EE;
#pragma unroll
  for (int j = 0; j < 4; j++) {
    const int r = m0 + wv * 16 + fg * 4 + j;
#pragma unroll
    for (int nt = 0; nt < 4; nt++)
      dst[(size_t)r * EE + nt * 16 + fr] = acc[nt][j];
  }
}

// ---------------------------------------------------------------------------
// Kernel 2: reduce partials, sqrt(softplus), top-8, renormalize, scatter.
// Flags rows with selection margin < TAU for exact f32 recompute.
// ---------------------------------------------------------------------------
__global__ __launch_bounds__(256) void topk_kernel(
    const float* __restrict__ part, const float* __restrict__ bias,
    float* __restrict__ out, int nrows, int ksplit, int* __restrict__ counter,
    int* __restrict__ list) {
  const int lane = threadIdx.x & 63;
  const int row = blockIdx.x * 4 + (threadIdx.x >> 6);

  float logit = 0.0f;
  for (int s = 0; s < ksplit; s++)
    logit += part[(size_t)s * nrows * EE + (size_t)row * EE + lane];

  float sp = (logit > 0.0f) ? (logit + log1pf(expf(-logit)))
                            : log1pf(expf(logit));
  float score = sqrtf(sp);
  float sel = score + bias[lane];

  float denom = 0.0f, v8 = 0.0f;
  bool chosen = false;
#pragma unroll
  for (int t = 0; t < 8; t++) {
    float v = sel;
    int idx = lane;
#pragma unroll
    for (int m = 1; m < 64; m <<= 1) {
      float ov = __shfl_xor(v, m, 64);
      int oi = __shfl_xor(idx, m, 64);
      if (ov > v || (ov == v && oi < idx)) { v = ov; idx = oi; }
    }
    float wscore = __shfl(score, idx, 64);
    denom += wscore;
    v8 = v;
    if (lane == idx) { chosen = true; sel = NEG_SENTINEL; }
  }
  float v9 = sel;
#pragma unroll
  for (int m = 1; m < 64; m <<= 1) v9 = fmaxf(v9, __shfl_xor(v9, m, 64));
  if (lane == 0 && (v8 - v9) < TAU) {
    int ix = atomicAdd(counter, 1);
    if (ix < MAXFIX) list[ix] = row;
  }

  denom = fmaxf(denom, 1e-12f);
  out[(size_t)row * EE + lane] = chosen ? (score / denom) : 0.0f;
  out[(size_t)nrows * EE + (size_t)row * EE + lane] = chosen ? 1.0f : 0.0f;
}

// ---------------------------------------------------------------------------
// Kernel 3a: exact-f32 partial dots for flagged rows, k-split 16 ways.
// ---------------------------------------------------------------------------
__global__ __launch_bounds__(256) void fixup_partial(
    const float* __restrict__ hidden, const float* __restrict__ gate_w,
    const int* __restrict__ counter, const int* __restrict__ list,
    float* __restrict__ part2) {
  __shared__ float red[EE][4];
  int cnt = *counter;
  if (cnt > MAXFIX) cnt = MAXFIX;
  const int total = cnt * 16;
  const int e = threadIdx.x & 63;
  const int q = threadIdx.x >> 6;
  for (int w = blockIdx.x; w < total; w += gridDim.x) {
    const int i = w >> 4;
    const int c = w & 15;
    const int row = list[i];
    const int kb = c * 256 + q * 64;
    const float* hp = hidden + (size_t)row * DD + kb;
    const float* wp = gate_w + (size_t)e * DD + kb;
    float s = 0.f;
#pragma unroll
    for (int k = 0; k < 64; k += 4) {
      float4 a = *(const float4*)(hp + k);
      float4 b = *(const float4*)(wp + k);
      s = fmaf(a.w, b.w, fmaf(a.z, b.z, fmaf(a.y, b.y, fmaf(a.x, b.x, s))));
    }
    red[e][q] = s;
    __syncthreads();
    if (threadIdx.x < EE)
      part2[(size_t)i * 1024 + threadIdx.x * 16 + c] =
          (red[threadIdx.x][0] + red[threadIdx.x][1]) +
          (red[threadIdx.x][2] + red[threadIdx.x][3]);
    __syncthreads();
  }
}

// ---------------------------------------------------------------------------
// Kernel 3b: sum the 16 chunks in fixed order, redo top-8 exactly, rewrite.
// ---------------------------------------------------------------------------
__global__ __launch_bounds__(256) void fixup_apply(
    const float* __restrict__ part2, const float* __restrict__ bias,
    const int* __restrict__ counter, const int* __restrict__ list,
    float* __restrict__ out, int nrows) {
  int cnt = *counter;
  if (cnt > MAXFIX) cnt = MAXFIX;
  const int lane = threadIdx.x & 63;
  const int wv = threadIdx.x >> 6;
  for (int i0 = blockIdx.x * 4; i0 < cnt; i0 += gridDim.x * 4) {
    const int i = i0 + wv;
    if (i >= cnt) continue;
    const int row = list[i];
    const float* pp = part2 + (size_t)i * 1024 + lane * 16;
    float logit = 0.f;
#pragma unroll
    for (int c = 0; c < 16; c++) logit += pp[c];

    float sp = (logit > 0.0f) ? (logit + log1pf(expf(-logit)))
                              : log1pf(expf(logit));
    float score = sqrtf(sp);
    float sel = score + bias[lane];
    float denom = 0.0f;
    bool chosen = false;
#pragma unroll
    for (int t = 0; t < 8; t++) {
      float v = sel;
      int idx = lane;
#pragma unroll
      for (int m = 1; m < 64; m <<= 1) {
        float ov = __shfl_xor(v, m, 64);
        int oi = __shfl_xor(idx, m, 64);
        if (ov > v || (ov == v && oi < idx)) { v = ov; idx = oi; }
      }
      float wscore = __shfl(score, idx, 64);
      denom += wscore;
      if (lane == idx) { chosen = true; sel = NEG_SENTINEL; }
    }
    denom = fmaxf(denom, 1e-12f);
    out[(size_t)row * EE + lane] = chosen ? (score / denom) : 0.0f;
    out[(size_t)nrows * EE + (size_t)row * EE + lane] = chosen ? 1.0f : 0.0f;
  }
}

// ---------------------------------------------------------------------------
extern "C" void kernel_launch(void* const* d_in, const int* in_sizes, int n_in,
                              void* d_out, int out_size, void* d_ws,
                              size_t ws_size, hipStream_t stream) {
  const float* hidden = (const float*)d_in[0];
  const float* gate_w = (const float*)d_in[1];
  const float* bias = (const float*)d_in[2];
  float* out = (float*)d_out;
  char* ws = (char*)d_ws;

  const int nrows = in_sizes[0] / DD;  // 16384

  size_t tail = (ws_size - 65536) & ~(size_t)255;
  int* counter = (int*)(ws + tail);
  int* list = counter + 1;
  float* part = (float*)ws;                                // 16 MiB (ks=4)
  float* part2 = (float*)(ws + (size_t)64 * 1024 * 1024);  // 64 MiB max
  const size_t per = (size_t)nrows * EE * sizeof(float);   // 4 MiB
  const int ksplit = (tail >= 4 * per) ? 4 : 2;

  hipMemsetAsync(counter, 0, sizeof(int), stream);

  dim3 block(256);
  if (ksplit == 4)
    gemm_mfma<4><<<dim3(nrows / 64, 4), block, 0, stream>>>(hidden, gate_w,
                                                            part, nrows);
  else
    gemm_mfma<2><<<dim3(nrows / 64, 2), block, 0, stream>>>(hidden, gate_w,
                                                            part, nrows);
  topk_kernel<<<dim3(nrows / 4), block, 0, stream>>>(part, bias, out, nrows,
                                                     ksplit, counter, list);
  fixup_partial<<<dim3(2048), block, 0, stream>>>(hidden, gate_w, counter,
                                                  list, part2);
  fixup_apply<<<dim3(512), block, 0, stream>>>(part2, bias, counter, list, out,
                                               nrows);
}